// Round 5
// baseline (416.749 us; speedup 1.0000x reference)
//
#include <hip/hip_runtime.h>
#include <stdint.h>
#include <math.h>

#define NB   2
#define NQ   100
#define NCLS 133
#define NCL1 134
#define HM   160
#define WM   160
#define HO   640
#define WO   640

static __device__ __forceinline__ int clampi(int v, int lo, int hi){ return v<lo?lo:(v>hi?hi:v); }

// ---------------- kernel 1: per-query softmax stats (f64) + compaction + zero areas ----------------
__global__ void k_classify(const float* __restrict__ logits, double* __restrict__ scores,
                           int* __restrict__ labels, int* __restrict__ keepf,
                           int* __restrict__ kq, int* __restrict__ Kc,
                           int* __restrict__ marea, int* __restrict__ oarea)
{
  int t = threadIdx.x;
  for (int i=t;i<NB*NQ;i+=blockDim.x){ marea[i]=0; oarea[i]=0; }
  if (t < NB*NQ){
    const float* l = logits + (size_t)t*NCL1;
    float mx = l[0]; int am = 0;
    for (int c=1;c<NCL1;++c){ float v=l[c]; if (v>mx){ mx=v; am=c; } }
    double s = 0.0;
    for (int c=0;c<NCL1;++c){
      s += exp((double)l[c] - (double)mx);
    }
    double sc = 1.0/s;                       // max softmax prob (f64)
    scores[t] = sc; labels[t] = am;
    keepf[t] = (am < NCLS && sc > 0.4) ? 1 : 0;
  }
  __syncthreads();
  if (t < NB){
    int k = 0;
    for (int q=0;q<NQ;++q) if (keepf[t*NQ+q]) kq[t*NQ + (k++)] = q;
    Kc[t] = k;
  }
}

// ---------------- kernel 2: sigmoid of kept masks (f64, stored f64) ----------------
__global__ void k_sigmoid(const float* __restrict__ masks, double* __restrict__ sig,
                          const int* __restrict__ keepf)
{
  int gid = blockIdx.x*blockDim.x + threadIdx.x;      // float4 index
  int bq  = gid / (HM*WM/4);
  if (!keepf[bq]) return;
  float4 v = reinterpret_cast<const float4*>(masks)[gid];
  double o0 = 1.0/(1.0+exp(-(double)v.x));
  double o1 = 1.0/(1.0+exp(-(double)v.y));
  double o2 = 1.0/(1.0+exp(-(double)v.z));
  double o3 = 1.0/(1.0+exp(-(double)v.w));
  double2 d0; d0.x=o0; d0.y=o1;
  double2 d1; d1.x=o2; d1.y=o3;
  reinterpret_cast<double2*>(sig)[gid*2]   = d0;
  reinterpret_cast<double2*>(sig)[gid*2+1] = d1;
}

// ---------------- kernel 3: per-pixel argmax over kept queries + areas (f64) ----------------
// thread = one input cell (ci,cj) -> 4x4 output pixels. Block = 16x8 cells = 64x32 out.
__global__ __launch_bounds__(128) void k_argmax(const double* __restrict__ sig,
        const double* __restrict__ scores, const int* __restrict__ kq,
        const int* __restrict__ Kc, uint32_t* __restrict__ mids,
        int* __restrict__ marea, int* __restrict__ oarea)
{
  __shared__ double patch[2][10][18];  // rows: 8 cells +2 halo, cols: 16 cells +2 halo
  __shared__ int hist[NQ];
  const int b   = blockIdx.z;
  const int tid = threadIdx.x;
  const int tx  = tid & 15, ty = tid >> 4;
  const int cj  = blockIdx.x*16 + tx;
  const int ci  = blockIdx.y*8  + ty;
  const int gr0 = blockIdx.y*8 - 1;
  const int gc0 = blockIdx.x*16 - 1;
  const int K   = Kc[b];

  for (int i=tid;i<NQ;i+=128) hist[i]=0;

  double best[4][4];
  int    bq[4][4];
  #pragma unroll
  for (int r=0;r<4;++r)
    #pragma unroll
    for (int s=0;s<4;++s){ best[r][s] = -1.0; bq[r][s] = 0; }

  if (K > 0){
    const double* sp = sig + (size_t)(b*NQ + kq[b*NQ])*HM*WM;
    for (int i=tid;i<180;i+=128){
      int pr=i/18, pc=i-18*pr;
      patch[0][pr][pc] = sp[clampi(gr0+pr,0,HM-1)*WM + clampi(gc0+pc,0,WM-1)];
    }
  }
  __syncthreads();

  for (int k=0;k<K;++k){
    const int    q  = kq[b*NQ+k];
    const double sc = scores[b*NQ+q];

    // prefetch next query's patch into registers (latency hides under compute)
    double pf0=0.0, pf1=0.0; int q2=-1;
    if (k+1 < K){
      q2 = kq[b*NQ+k+1];
      const double* sp = sig + (size_t)(b*NQ + q2)*HM*WM;
      { int i=tid;      int pr=i/18, pc=i-18*pr;
        pf0 = sp[clampi(gr0+pr,0,HM-1)*WM + clampi(gc0+pc,0,WM-1)]; }
      if (tid+128 < 180){ int i=tid+128; int pr=i/18, pc=i-18*pr;
        pf1 = sp[clampi(gr0+pr,0,HM-1)*WM + clampi(gc0+pc,0,WM-1)]; }
    }

    const int cb = k & 1;
    double v[3][3];
    #pragma unroll
    for (int rr=0;rr<3;++rr)
      #pragma unroll
      for (int cc=0;cc<3;++cc)
        v[rr][cc] = patch[cb][ty+rr][tx+cc];

    int cnt = 0;
    #pragma unroll
    for (int r=0;r<4;++r){
      const double wa = (r==0)?0.375:(r==1)?0.125:(r==2)?0.875:0.625;
      const double wb = (r==0)?0.625:(r==1)?0.875:(r==2)?0.125:0.375;
      const int ra = (r<2)?0:1, rb = ra+1;
      // image-edge rows renormalize to a single weight 1.0 -> exact copy
      const bool vedge = (r<2) ? (ci==0) : (ci==HM-1);
      const int  vsel  = (r<2) ? rb : ra;
      double t0 = vedge ? v[vsel][0] : (wa*v[ra][0] + wb*v[rb][0]);
      double t1 = vedge ? v[vsel][1] : (wa*v[ra][1] + wb*v[rb][1]);
      double t2 = vedge ? v[vsel][2] : (wa*v[ra][2] + wb*v[rb][2]);
      double u[4];
      u[0] = (cj==0)    ? t1 : (0.375*t0 + 0.625*t1);
      u[1] = (cj==0)    ? t1 : (0.125*t0 + 0.875*t1);
      u[2] = (cj==WM-1) ? t1 : (0.875*t1 + 0.125*t2);
      u[3] = (cj==WM-1) ? t1 : (0.625*t1 + 0.375*t2);
      #pragma unroll
      for (int s=0;s<4;++s){
        cnt += (u[s] >= 0.5) ? 1 : 0;
        double val = sc*u[s];
        if (val > best[r][s]){ best[r][s] = val; bq[r][s] = q; }
      }
    }
    // orig_area: reduce across the wave, one atomic per wave per query
    #pragma unroll
    for (int o2=32;o2>0;o2>>=1) cnt += __shfl_down(cnt, o2);
    if ((tid & 63) == 0) atomicAdd(&oarea[b*NQ+q], cnt);

    __syncthreads();
    if (q2 >= 0){
      { int i=tid;        patch[cb^1][i/18][i%18] = pf0; }
      if (tid+128 < 180){ int i=tid+128; patch[cb^1][i/18][i%18] = pf1; }
    }
    __syncthreads();
  }

  // winner ids packed 4-per-u32 (x phases), one store per output row
  #pragma unroll
  for (int r=0;r<4;++r){
    uint32_t w = (uint32_t)bq[r][0] | ((uint32_t)bq[r][1]<<8)
               | ((uint32_t)bq[r][2]<<16) | ((uint32_t)bq[r][3]<<24);
    int y = 4*ci + r;
    mids[(b*HO + y)*(WO/4) + cj] = w;
  }
  #pragma unroll
  for (int r=0;r<4;++r)
    #pragma unroll
    for (int s=0;s<4;++s)
      atomicAdd(&hist[bq[r][s]], 1);
  __syncthreads();
  for (int i=tid;i<NQ;i+=128)
    if (hist[i]) atomicAdd(&marea[b*NQ+i], hist[i]);
}

// ---------------- kernel 4: accept test + cumsum ids + per-class lists ----------------
__global__ void k_finalize(const int* __restrict__ keepf, const int* __restrict__ labels,
                           const int* __restrict__ marea, const int* __restrict__ oarea,
                           float* __restrict__ fid, int* __restrict__ chanoff,
                           int* __restrict__ sortedq)
{
  const int b = blockIdx.x;
  const int tid = threadIdx.x;
  __shared__ int acc[NQ], lab[NQ], cntS[NCLS], start[NCLS];
  if (tid < NQ){
    int i = b*NQ + tid;
    int ma = marea[i], oa = oarea[i];
    acc[tid] = (keepf[i] && ma>0 && oa>0 && ((double)ma > 0.8*(double)oa)) ? 1 : 0;
    lab[tid] = labels[i];
  }
  if (tid < NCLS) cntS[tid]=0;
  __syncthreads();
  if (tid == 0){
    int A = 0;
    for (int q=0;q<NQ;++q){
      if (acc[q]){ A++; fid[b*NQ+q] = (float)A; cntS[lab[q]]++; }
      else fid[b*NQ+q] = 0.0f;
    }
    int off = 0;
    for (int c=0;c<NCLS;++c){ start[c]=off; chanoff[b*NCL1+c]=off; off += cntS[c]; }
    chanoff[b*NCL1+NCLS] = off;
    for (int q=0;q<NQ;++q)
      if (acc[q]){ int c=lab[q]; sortedq[b*NQ + start[c]] = q; start[c]++; }
  }
}

// ---------------- kernel 5: panoptic ids (as float values) ----------------
__global__ void k_pan(const uint32_t* __restrict__ mids, const float* __restrict__ fid,
                      float* __restrict__ out)
{
  int t = blockIdx.x*blockDim.x + threadIdx.x;        // 0..204799 (float4 units)
  int b = t / (HO*WO/4);
  uint32_t w = mids[t];
  float4 o;
  o.x = fid[b*NQ + (w & 255u)];
  o.y = fid[b*NQ + ((w>>8) & 255u)];
  o.z = fid[b*NQ + ((w>>16) & 255u)];
  o.w = fid[b*NQ + (w>>24)];
  reinterpret_cast<float4*>(out)[(size_t)NB*NCLS*(HO*(size_t)WO/4) + t] = o;
}

// ---------------- kernel 6: sem_seg (zeros + per-class max of upsampled masks, f64 math) ----------------
__global__ void k_sem(const double* __restrict__ sig, const int* __restrict__ chanoff,
                      const int* __restrict__ sortedq, float* __restrict__ out)
{
  const int c = blockIdx.y, b = blockIdx.z;
  const int p4 = blockIdx.x*blockDim.x + threadIdx.x;   // 0..102399
  const int s0 = chanoff[b*NCL1+c], s1 = chanoff[b*NCL1+c+1];
  const int y  = p4 / (WO/4);
  const int cj = p4 - y*(WO/4);
  double o0=0.0, o1=0.0, o2=0.0, o3=0.0;
  if (s1 > s0){
    const int ci = y >> 2, r = y & 3;
    const int ra = (r<2) ? max(ci-1,0) : ci;
    const int rb = (r<2) ? ci : min(ci+1, HM-1);
    const double wa = (r==0)?0.375:(r==1)?0.125:(r==2)?0.875:0.625;
    const double wb = (r==0)?0.625:(r==1)?0.875:(r==2)?0.125:0.375;
    const bool vedge = (r<2) ? (ci==0) : (ci==HM-1);
    const int cm = max(cj-1,0), cp = min(cj+1, WM-1);
    for (int i=s0;i<s1;++i){
      const int q = sortedq[b*NQ+i];
      const double* sp = sig + (size_t)(b*NQ+q)*HM*WM;
      const double* Ra = sp + ra*WM;
      const double* Rb = sp + rb*WM;
      double am=Ra[cm], a0=Ra[cj], ap=Ra[cp];
      double bm=Rb[cm], b0=Rb[cj], bp=Rb[cp];
      // image-edge rows: single renormalized weight 1.0 -> exact copy of valid row
      double t0 = vedge ? ((r<2) ? bm : am) : (wa*am + wb*bm);
      double t1 = vedge ? ((r<2) ? b0 : a0) : (wa*a0 + wb*b0);
      double t2 = vedge ? ((r<2) ? bp : ap) : (wa*ap + wb*bp);
      double u0 = (cj==0)    ? t1 : (0.375*t0 + 0.625*t1);
      double u1 = (cj==0)    ? t1 : (0.125*t0 + 0.875*t1);
      double u2 = (cj==WM-1) ? t1 : (0.875*t1 + 0.125*t2);
      double u3 = (cj==WM-1) ? t1 : (0.625*t1 + 0.375*t2);
      o0 = fmax(o0, u0);
      o1 = fmax(o1, u1);
      o2 = fmax(o2, u2);
      o3 = fmax(o3, u3);
    }
  }
  float4 o; o.x=(float)o0; o.y=(float)o1; o.z=(float)o2; o.w=(float)o3;
  reinterpret_cast<float4*>(out)[((size_t)(b*NCLS+c))*(HO*WO/4) + p4] = o;
}

extern "C" void kernel_launch(void* const* d_in, const int* in_sizes, int n_in,
                              void* d_out, int out_size, void* d_ws, size_t ws_size,
                              hipStream_t stream)
{
  const float* logits = (const float*)d_in[0];
  const float* masks  = (const float*)d_in[1];
  float* out = (float*)d_out;

  char* ws = (char*)d_ws;
  size_t off = 0;
  auto alloc = [&](size_t bytes)->void*{
    void* p = ws + off; off = (off + bytes + 255) & ~(size_t)255; return p;
  };
  double*   sig     = (double*)  alloc((size_t)NB*NQ*HM*WM*sizeof(double)); // 40.96 MB
  uint32_t* mids    = (uint32_t*)alloc((size_t)NB*HO*(WO/4)*sizeof(uint32_t));
  double*   scores  = (double*)  alloc(NB*NQ*sizeof(double));
  int*      labels  = (int*)     alloc(NB*NQ*sizeof(int));
  int*      keepf   = (int*)     alloc(NB*NQ*sizeof(int));
  int*      kq      = (int*)     alloc(NB*NQ*sizeof(int));
  int*      Kc      = (int*)     alloc(NB*sizeof(int));
  int*      marea   = (int*)     alloc(NB*NQ*sizeof(int));
  int*      oarea   = (int*)     alloc(NB*NQ*sizeof(int));
  float*    fid     = (float*)   alloc(NB*NQ*sizeof(float));
  int*      chanoff = (int*)     alloc(NB*NCL1*sizeof(int));
  int*      sortedq = (int*)     alloc(NB*NQ*sizeof(int));

  hipLaunchKernelGGL(k_classify, dim3(1), dim3(256), 0, stream,
                     logits, scores, labels, keepf, kq, Kc, marea, oarea);
  hipLaunchKernelGGL(k_sigmoid, dim3((NB*NQ*HM*WM/4)/256), dim3(256), 0, stream,
                     masks, sig, keepf);
  hipLaunchKernelGGL(k_argmax, dim3(WM/16, HM/8, NB), dim3(128), 0, stream,
                     sig, scores, kq, Kc, mids, marea, oarea);
  hipLaunchKernelGGL(k_finalize, dim3(NB), dim3(192), 0, stream,
                     keepf, labels, marea, oarea, fid, chanoff, sortedq);
  hipLaunchKernelGGL(k_pan, dim3((NB*HO*WO/4)/256), dim3(256), 0, stream,
                     mids, fid, out);
  hipLaunchKernelGGL(k_sem, dim3((HO*WO/4)/256, NCLS, NB), dim3(256), 0, stream,
                     sig, chanoff, sortedq, out);
}

// Round 6
// 331.421 us; speedup vs baseline: 1.2575x; 1.2575x over previous
//
#include <hip/hip_runtime.h>
#include <stdint.h>
#include <math.h>

#define NB   2
#define NQ   100
#define NCLS 133
#define NCL1 134
#define HM   160
#define WM   160
#define HO   640
#define WO   640
#define G    4          // query-split groups for argmax
#define NCELL (HM*WM)   // 25600 cells per batch

static __device__ __forceinline__ int clampi(int v, int lo, int hi){ return v<lo?lo:(v>hi?hi:v); }
static __device__ __forceinline__ double dsig(float x){ return 1.0/(1.0+exp(-(double)x)); }

// ---------------- kernel 1: per-query softmax stats (f64) + compaction + zero areas ----------------
__global__ void k_classify(const float* __restrict__ logits, double* __restrict__ scores,
                           int* __restrict__ labels, int* __restrict__ keepf,
                           int* __restrict__ kq, int* __restrict__ Kc,
                           int* __restrict__ marea, int* __restrict__ oarea)
{
  int t = threadIdx.x;
  for (int i=t;i<NB*NQ;i+=blockDim.x){ marea[i]=0; oarea[i]=0; }
  if (t < NB*NQ){
    const float* l = logits + (size_t)t*NCL1;
    float mx = l[0]; int am = 0;
    for (int c=1;c<NCL1;++c){ float v=l[c]; if (v>mx){ mx=v; am=c; } }
    double s = 0.0;
    for (int c=0;c<NCL1;++c) s += exp((double)l[c] - (double)mx);
    double sc = 1.0/s;
    scores[t] = sc; labels[t] = am;
    keepf[t] = (am < NCLS && sc > 0.4) ? 1 : 0;
  }
  __syncthreads();
  if (t < NB){
    int k = 0;
    for (int q=0;q<NQ;++q) if (keepf[t*NQ+q]) kq[t*NQ + (k++)] = q;
    Kc[t] = k;
  }
}

// ---------------- kernel 2: f32 sigmoid of kept masks (for sem only) ----------------
__global__ void k_sigmoid32(const float* __restrict__ masks, float* __restrict__ sig32,
                            const int* __restrict__ keepf)
{
  int gid = blockIdx.x*blockDim.x + threadIdx.x;      // float4 index
  int bq  = gid / (HM*WM/4);
  if (!keepf[bq]) return;
  float4 v = reinterpret_cast<const float4*>(masks)[gid];
  float4 o;
  o.x = (float)dsig(v.x);
  o.y = (float)dsig(v.y);
  o.z = (float)dsig(v.z);
  o.w = (float)dsig(v.w);
  reinterpret_cast<float4*>(sig32)[gid] = o;
}

// ---------------- kernel 3a: split-K per-pixel argmax partials (f64, sigmoid fused) ----------------
// thread = one input cell -> 4x4 output pixels. Block = 16x8 cells. blockIdx.z = b*G+g.
__global__ __launch_bounds__(128) void k_argmax_part(const float* __restrict__ masks,
        const double* __restrict__ scores, const int* __restrict__ kq,
        const int* __restrict__ Kc, double* __restrict__ pbest, int* __restrict__ pq,
        int* __restrict__ oarea)
{
  __shared__ double patch[2][10][18];
  const int b   = blockIdx.z / G;
  const int g   = blockIdx.z % G;
  const int tid = threadIdx.x;
  const int tx  = tid & 15, ty = tid >> 4;
  const int cj  = blockIdx.x*16 + tx;
  const int ci  = blockIdx.y*8  + ty;
  const int gr0 = blockIdx.y*8 - 1;
  const int gc0 = blockIdx.x*16 - 1;
  const int K   = Kc[b];
  const int Kg  = (K + G - 1) / G;
  const int k0  = g*Kg;
  const int k1  = min(K, k0 + Kg);

  double best[4][4];
  int    bq[4][4];
  #pragma unroll
  for (int r=0;r<4;++r)
    #pragma unroll
    for (int s=0;s<4;++s){ best[r][s] = -1.0; bq[r][s] = 0; }

  if (k0 < k1){
    const float* mp = masks + (size_t)(b*NQ + kq[b*NQ+k0])*HM*WM;
    for (int i=tid;i<180;i+=128){
      int pr=i/18, pc=i-18*pr;
      patch[0][pr][pc] = dsig(mp[clampi(gr0+pr,0,HM-1)*WM + clampi(gc0+pc,0,WM-1)]);
    }
  }
  __syncthreads();

  for (int k=k0;k<k1;++k){
    const int    q  = kq[b*NQ+k];
    const double sc = scores[b*NQ+q];

    // prefetch next query's patch (sigmoid applied in-register)
    double pf0=0.0, pf1=0.0; int q2=-1;
    if (k+1 < k1){
      q2 = kq[b*NQ+k+1];
      const float* mp = masks + (size_t)(b*NQ + q2)*HM*WM;
      { int i=tid;      int pr=i/18, pc=i-18*pr;
        pf0 = dsig(mp[clampi(gr0+pr,0,HM-1)*WM + clampi(gc0+pc,0,WM-1)]); }
      if (tid+128 < 180){ int i=tid+128; int pr=i/18, pc=i-18*pr;
        pf1 = dsig(mp[clampi(gr0+pr,0,HM-1)*WM + clampi(gc0+pc,0,WM-1)]); }
    }

    const int cb = (k - k0) & 1;
    double v[3][3];
    #pragma unroll
    for (int rr=0;rr<3;++rr)
      #pragma unroll
      for (int cc=0;cc<3;++cc)
        v[rr][cc] = patch[cb][ty+rr][tx+cc];

    int cnt = 0;
    #pragma unroll
    for (int r=0;r<4;++r){
      const double wa = (r==0)?0.375:(r==1)?0.125:(r==2)?0.875:0.625;
      const double wb = (r==0)?0.625:(r==1)?0.875:(r==2)?0.125:0.375;
      const int ra = (r<2)?0:1, rb = ra+1;
      const bool vedge = (r<2) ? (ci==0) : (ci==HM-1);
      const int  vsel  = (r<2) ? rb : ra;
      double t0 = vedge ? v[vsel][0] : (wa*v[ra][0] + wb*v[rb][0]);
      double t1 = vedge ? v[vsel][1] : (wa*v[ra][1] + wb*v[rb][1]);
      double t2 = vedge ? v[vsel][2] : (wa*v[ra][2] + wb*v[rb][2]);
      double u[4];
      u[0] = (cj==0)    ? t1 : (0.375*t0 + 0.625*t1);
      u[1] = (cj==0)    ? t1 : (0.125*t0 + 0.875*t1);
      u[2] = (cj==WM-1) ? t1 : (0.875*t1 + 0.125*t2);
      u[3] = (cj==WM-1) ? t1 : (0.625*t1 + 0.375*t2);
      #pragma unroll
      for (int s=0;s<4;++s){
        cnt += (u[s] >= 0.5) ? 1 : 0;
        double val = sc*u[s];
        if (val > best[r][s]){ best[r][s] = val; bq[r][s] = q; }
      }
    }
    // orig_area: groups own disjoint queries -> plain atomic accumulation
    #pragma unroll
    for (int o2=32;o2>0;o2>>=1) cnt += __shfl_down(cnt, o2);
    if ((tid & 63) == 0) atomicAdd(&oarea[b*NQ+q], cnt);

    __syncthreads();
    if (q2 >= 0){
      { int i=tid;        patch[cb^1][i/18][i%18] = pf0; }
      if (tid+128 < 180){ int i=tid+128; patch[cb^1][i/18][i%18] = pf1; }
    }
    __syncthreads();
  }

  // write partials: plane-major so consecutive cells are coalesced
  const int cell = ci*WM + cj;
  #pragma unroll
  for (int r=0;r<4;++r)
    #pragma unroll
    for (int s=0;s<4;++s){
      size_t idx = ((size_t)((b*G + g)*16 + r*4 + s))*NCELL + cell;
      pbest[idx] = best[r][s];
      pq[idx]    = bq[r][s];
    }
}

// ---------------- kernel 3b: combine partials -> winners, mask areas ----------------
__global__ __launch_bounds__(128) void k_argmax_comb(const double* __restrict__ pbest,
        const int* __restrict__ pq, uint32_t* __restrict__ mids, int* __restrict__ marea)
{
  __shared__ int hist[NQ];
  const int b   = blockIdx.z;
  const int tid = threadIdx.x;
  const int tx  = tid & 15, ty = tid >> 4;
  const int cj  = blockIdx.x*16 + tx;
  const int ci  = blockIdx.y*8  + ty;
  const int cell= ci*WM + cj;

  for (int i=tid;i<NQ;i+=128) hist[i]=0;
  __syncthreads();

  int bqa[16];
  #pragma unroll
  for (int rs=0;rs<16;++rs){
    double cur = -1.0; int q = 0;
    #pragma unroll
    for (int g2=0;g2<G;++g2){
      size_t idx = ((size_t)((b*G + g2)*16 + rs))*NCELL + cell;
      double v = pbest[idx];
      if (v > cur){ cur = v; q = pq[idx]; }   // ascending-q groups: strict > keeps first max
    }
    bqa[rs] = q;
  }

  #pragma unroll
  for (int r=0;r<4;++r){
    uint32_t w = (uint32_t)bqa[r*4+0] | ((uint32_t)bqa[r*4+1]<<8)
               | ((uint32_t)bqa[r*4+2]<<16) | ((uint32_t)bqa[r*4+3]<<24);
    int y = 4*ci + r;
    mids[(b*HO + y)*(WO/4) + cj] = w;
  }
  #pragma unroll
  for (int rs=0;rs<16;++rs)
    atomicAdd(&hist[bqa[rs]], 1);
  __syncthreads();
  for (int i=tid;i<NQ;i+=128)
    if (hist[i]) atomicAdd(&marea[b*NQ+i], hist[i]);
}

// ---------------- kernel 4: accept test + cumsum ids + per-class lists ----------------
__global__ void k_finalize(const int* __restrict__ keepf, const int* __restrict__ labels,
                           const int* __restrict__ marea, const int* __restrict__ oarea,
                           float* __restrict__ fid, int* __restrict__ chanoff,
                           int* __restrict__ sortedq)
{
  const int b = blockIdx.x;
  const int tid = threadIdx.x;
  __shared__ int acc[NQ], lab[NQ], cntS[NCLS], start[NCLS];
  if (tid < NQ){
    int i = b*NQ + tid;
    int ma = marea[i], oa = oarea[i];
    acc[tid] = (keepf[i] && ma>0 && oa>0 && ((double)ma > 0.8*(double)oa)) ? 1 : 0;
    lab[tid] = labels[i];
  }
  if (tid < NCLS) cntS[tid]=0;
  __syncthreads();
  if (tid == 0){
    int A = 0;
    for (int q=0;q<NQ;++q){
      if (acc[q]){ A++; fid[b*NQ+q] = (float)A; cntS[lab[q]]++; }
      else fid[b*NQ+q] = 0.0f;
    }
    int off = 0;
    for (int c=0;c<NCLS;++c){ start[c]=off; chanoff[b*NCL1+c]=off; off += cntS[c]; }
    chanoff[b*NCL1+NCLS] = off;
    for (int q=0;q<NQ;++q)
      if (acc[q]){ int c=lab[q]; sortedq[b*NQ + start[c]] = q; start[c]++; }
  }
}

// ---------------- kernel 5: panoptic ids (as float values) ----------------
__global__ void k_pan(const uint32_t* __restrict__ mids, const float* __restrict__ fid,
                      float* __restrict__ out)
{
  int t = blockIdx.x*blockDim.x + threadIdx.x;        // float4 units
  int b = t / (HO*WO/4);
  uint32_t w = mids[t];
  float4 o;
  o.x = fid[b*NQ + (w & 255u)];
  o.y = fid[b*NQ + ((w>>8) & 255u)];
  o.z = fid[b*NQ + ((w>>16) & 255u)];
  o.w = fid[b*NQ + (w>>24)];
  reinterpret_cast<float4*>(out)[(size_t)NB*NCLS*(HO*(size_t)WO/4) + t] = o;
}

// ---------------- kernel 6: sem_seg (f32 path — loose tolerance) ----------------
__global__ void k_sem(const float* __restrict__ sig32, const int* __restrict__ chanoff,
                      const int* __restrict__ sortedq, float* __restrict__ out)
{
  const int c = blockIdx.y, b = blockIdx.z;
  const int p4 = blockIdx.x*blockDim.x + threadIdx.x;   // 0..102399
  const int s0 = chanoff[b*NCL1+c], s1 = chanoff[b*NCL1+c+1];
  const int y  = p4 / (WO/4);
  const int cj = p4 - y*(WO/4);
  float4 o = make_float4(0.f,0.f,0.f,0.f);
  if (s1 > s0){
    const int ci = y >> 2, r = y & 3;
    const int ra = (r<2) ? max(ci-1,0) : ci;
    const int rb = (r<2) ? ci : min(ci+1, HM-1);
    const float wa = (r==0)?0.375f:(r==1)?0.125f:(r==2)?0.875f:0.625f;
    const float wb = (r==0)?0.625f:(r==1)?0.875f:(r==2)?0.125f:0.375f;
    const bool vedge = (r<2) ? (ci==0) : (ci==HM-1);
    const int cm = max(cj-1,0), cp = min(cj+1, WM-1);
    for (int i=s0;i<s1;++i){
      const int q = sortedq[b*NQ+i];
      const float* sp = sig32 + (size_t)(b*NQ+q)*HM*WM;
      const float* Ra = sp + ra*WM;
      const float* Rb = sp + rb*WM;
      float am=Ra[cm], a0=Ra[cj], ap=Ra[cp];
      float bm=Rb[cm], b0=Rb[cj], bp=Rb[cp];
      float t0 = vedge ? ((r<2) ? bm : am) : (wa*am + wb*bm);
      float t1 = vedge ? ((r<2) ? b0 : a0) : (wa*a0 + wb*b0);
      float t2 = vedge ? ((r<2) ? bp : ap) : (wa*ap + wb*bp);
      float u0 = (cj==0)    ? t1 : (0.375f*t0 + 0.625f*t1);
      float u1 = (cj==0)    ? t1 : (0.125f*t0 + 0.875f*t1);
      float u2 = (cj==WM-1) ? t1 : (0.875f*t1 + 0.125f*t2);
      float u3 = (cj==WM-1) ? t1 : (0.625f*t1 + 0.375f*t2);
      o.x = fmaxf(o.x, u0);
      o.y = fmaxf(o.y, u1);
      o.z = fmaxf(o.z, u2);
      o.w = fmaxf(o.w, u3);
    }
  }
  reinterpret_cast<float4*>(out)[((size_t)(b*NCLS+c))*(HO*WO/4) + p4] = o;
}

extern "C" void kernel_launch(void* const* d_in, const int* in_sizes, int n_in,
                              void* d_out, int out_size, void* d_ws, size_t ws_size,
                              hipStream_t stream)
{
  const float* logits = (const float*)d_in[0];
  const float* masks  = (const float*)d_in[1];
  float* out = (float*)d_out;

  char* ws = (char*)d_ws;
  size_t off = 0;
  auto alloc = [&](size_t bytes)->void*{
    void* p = ws + off; off = (off + bytes + 255) & ~(size_t)255; return p;
  };
  float*    sig32   = (float*)   alloc((size_t)NB*NQ*HM*WM*sizeof(float));     // 20.5 MB
  double*   pbest   = (double*)  alloc((size_t)NB*G*16*NCELL*sizeof(double));  // 26.2 MB
  int*      pq      = (int*)     alloc((size_t)NB*G*16*NCELL*sizeof(int));     // 13.1 MB
  uint32_t* mids    = (uint32_t*)alloc((size_t)NB*HO*(WO/4)*sizeof(uint32_t));
  double*   scores  = (double*)  alloc(NB*NQ*sizeof(double));
  int*      labels  = (int*)     alloc(NB*NQ*sizeof(int));
  int*      keepf   = (int*)     alloc(NB*NQ*sizeof(int));
  int*      kq      = (int*)     alloc(NB*NQ*sizeof(int));
  int*      Kc      = (int*)     alloc(NB*sizeof(int));
  int*      marea   = (int*)     alloc(NB*NQ*sizeof(int));
  int*      oarea   = (int*)     alloc(NB*NQ*sizeof(int));
  float*    fid     = (float*)   alloc(NB*NQ*sizeof(float));
  int*      chanoff = (int*)     alloc(NB*NCL1*sizeof(int));
  int*      sortedq = (int*)     alloc(NB*NQ*sizeof(int));

  hipLaunchKernelGGL(k_classify, dim3(1), dim3(256), 0, stream,
                     logits, scores, labels, keepf, kq, Kc, marea, oarea);
  hipLaunchKernelGGL(k_sigmoid32, dim3((NB*NQ*HM*WM/4)/256), dim3(256), 0, stream,
                     masks, sig32, keepf);
  hipLaunchKernelGGL(k_argmax_part, dim3(WM/16, HM/8, NB*G), dim3(128), 0, stream,
                     masks, scores, kq, Kc, pbest, pq, oarea);
  hipLaunchKernelGGL(k_argmax_comb, dim3(WM/16, HM/8, NB), dim3(128), 0, stream,
                     pbest, pq, mids, marea);
  hipLaunchKernelGGL(k_finalize, dim3(NB), dim3(192), 0, stream,
                     keepf, labels, marea, oarea, fid, chanoff, sortedq);
  hipLaunchKernelGGL(k_pan, dim3((NB*HO*WO/4)/256), dim3(256), 0, stream,
                     mids, fid, out);
  hipLaunchKernelGGL(k_sem, dim3((HO*WO/4)/256, NCLS, NB), dim3(256), 0, stream,
                     sig32, chanoff, sortedq, out);
}